// Round 6
// baseline (576.124 us; speedup 1.0000x reference)
//
#include <hip/hip_runtime.h>
#include <stdint.h>
#include <stddef.h>

#define B_   8
#define NQ_  1024
#define NKV_ 2048
#define D_   1024
#define H_   16
#define HD_  64

typedef __bf16 bf16;
typedef __bf16 bf16x4 __attribute__((ext_vector_type(4)));
typedef __bf16 bf16x8 __attribute__((ext_vector_type(8)));
typedef float  f32x2  __attribute__((ext_vector_type(2)));
typedef float  f32x4  __attribute__((ext_vector_type(4)));
typedef float  f32x16 __attribute__((ext_vector_type(16)));
typedef unsigned int u32;
typedef u32 u32x2 __attribute__((ext_vector_type(2)));
typedef u32 u32x4 __attribute__((ext_vector_type(4)));
typedef unsigned short u16;

__device__ __forceinline__ void gload_lds16(const void* g, void* l) {
  __builtin_amdgcn_global_load_lds((const __attribute__((address_space(1))) void*)g,
                                   (__attribute__((address_space(3))) void*)l, 16, 0, 0);
}

// explicit, unambiguous bf16-pair pack (compiler may fuse to v_cvt_pk_bf16_f32)
__device__ __forceinline__ u32 pack2(float a, float b) {
  u16 ua = __builtin_bit_cast(u16, (bf16)a);
  u16 ub = __builtin_bit_cast(u16, (bf16)b);
  return (u32)ua | ((u32)ub << 16);
}

// ---------------- weight fp32 -> bf16 ----------------
__global__ void cvt_w_kernel(const float* __restrict__ w0, const float* __restrict__ w1,
                             const float* __restrict__ w2, const float* __restrict__ w3,
                             bf16* __restrict__ o0, bf16* __restrict__ o1,
                             bf16* __restrict__ o2, bf16* __restrict__ o3) {
  const float* s; bf16* d;
  switch (blockIdx.y) {
    case 0: s = w0; d = o0; break;
    case 1: s = w1; d = o1; break;
    case 2: s = w2; d = o2; break;
    default: s = w3; d = o3; break;
  }
  int i = (blockIdx.x * 256 + threadIdx.x) * 4;
  float4 v = *(const float4*)(s + i);
  bf16x4 t = { (bf16)v.x, (bf16)v.y, (bf16)v.z, (bf16)v.w };
  *(bf16x4*)(d + i) = t;
}

// ---------------- LayerNorm rows of 1024, fp32 -> bf16 ----------------
__global__ void ln_bf16_kernel(const float* __restrict__ x, bf16* __restrict__ y) {
  int w = threadIdx.x >> 6, l = threadIdx.x & 63;
  int row = blockIdx.x * 4 + w;
  const float* xr = x + (size_t)row * D_;
  float4 v[4];
#pragma unroll
  for (int k = 0; k < 4; ++k) v[k] = *(const float4*)(xr + k * 256 + l * 4);
  float s = 0.f, ss = 0.f;
#pragma unroll
  for (int k = 0; k < 4; ++k) {
    s  += v[k].x + v[k].y + v[k].z + v[k].w;
    ss += v[k].x * v[k].x + v[k].y * v[k].y + v[k].z * v[k].z + v[k].w * v[k].w;
  }
#pragma unroll
  for (int m = 1; m < 64; m <<= 1) { s += __shfl_xor(s, m); ss += __shfl_xor(ss, m); }
  float mu = s * (1.f / D_);
  float var = ss * (1.f / D_) - mu * mu;
  float rs = rsqrtf(var + 1e-5f);
  bf16* yr = y + (size_t)row * D_;
#pragma unroll
  for (int k = 0; k < 4; ++k) {
    bf16x4 t = { (bf16)((v[k].x - mu) * rs), (bf16)((v[k].y - mu) * rs),
                 (bf16)((v[k].z - mu) * rs), (bf16)((v[k].w - mu) * rs) };
    *(bf16x4*)(yr + k * 256 + l * 4) = t;
  }
}

// ---------------- GEMM: C[m,n] = sum_k A[m,k]*Bw[n,k] (+bias, epilogue) ----------
__device__ __forceinline__ int swz64(int row, int slot) {  // 64B rows, 4x16B slots
  return row * 64 + ((slot ^ ((row >> 1) & 3)) << 4);
}

template<int EPI>
__global__ __launch_bounds__(256)
void gemm_bt(const bf16* __restrict__ A, const bf16* __restrict__ Bw,
             const float* __restrict__ bias,
             const float* __restrict__ cosT, const float* __restrict__ sinT,
             void* __restrict__ outp, int seq_shift) {
  __shared__ bf16 As[2][128 * 32];
  __shared__ bf16 Bs[2][128 * 32];
  const int tid = threadIdx.x;
  const int w = tid >> 6, l = tid & 63;
  const int wr = w >> 1, wc = w & 1;
  const int lg = l >> 4, lr = l & 15;
  const int mbase = blockIdx.y * 128, nbase = blockIdx.x * 128;

  f32x4 acc[4][4] = {};

  auto stage = [&](int k0, int buf) {
#pragma unroll
    for (int i = 0; i < 2; ++i) {
      int S = i * 256 + tid;
      int row = S >> 2, st = S & 3;
      int gs = st ^ ((row >> 1) & 3);
      gload_lds16((const char*)(A + ((size_t)(mbase + row) * 1024 + k0)) + gs * 16,
                  (char*)&As[buf][0] + (i * 256 + w * 64) * 16);
    }
#pragma unroll
    for (int i = 0; i < 2; ++i) {
      int S = i * 256 + tid;
      int row = S >> 2, st = S & 3;
      int gs = st ^ ((row >> 1) & 3);
      gload_lds16((const char*)(Bw + ((size_t)(nbase + row) * 1024 + k0)) + gs * 16,
                  (char*)&Bs[buf][0] + (i * 256 + w * 64) * 16);
    }
  };

  stage(0, 0);
  __syncthreads();
  for (int it = 0; it < 32; ++it) {
    int buf = it & 1;
    if (it + 1 < 32) stage((it + 1) * 32, buf ^ 1);
    bf16x8 af[4], bfr[4];
#pragma unroll
    for (int fr = 0; fr < 4; ++fr)
      af[fr] = *(const bf16x8*)((const char*)&As[buf][0] + swz64(wr * 64 + fr * 16 + lr, lg));
#pragma unroll
    for (int fc = 0; fc < 4; ++fc)
      bfr[fc] = *(const bf16x8*)((const char*)&Bs[buf][0] + swz64(wc * 64 + fc * 16 + lr, lg));
#pragma unroll
    for (int fr = 0; fr < 4; ++fr)
#pragma unroll
      for (int fc = 0; fc < 4; ++fc)
        acc[fr][fc] = __builtin_amdgcn_mfma_f32_16x16x32_bf16(af[fr], bfr[fc], acc[fr][fc], 0, 0, 0);
    __syncthreads();
  }

#pragma unroll
  for (int fr = 0; fr < 4; ++fr)
#pragma unroll
    for (int r = 0; r < 4; ++r) {
      int mrow = mbase + wr * 64 + fr * 16 + lg * 4 + r;
#pragma unroll
      for (int fc = 0; fc < 4; ++fc) {
        int n = nbase + wc * 64 + fc * 16 + lr;
        float x = acc[fr][fc][r];
        if (EPI == 0) {
          float xb  = x + bias[n];
          float xpb = acc[fr][fc ^ 2][r] + bias[n ^ 32];
          int d = n & 63, h = n >> 6;
          int seqN = 1 << seq_shift;
          int pos = mrow & (seqN - 1), bi = mrow >> seq_shift;
          float c = cosT[pos * 64 + d], s2 = sinT[pos * 64 + d];
          float yv = xb * c + ((d < 32) ? -xpb : xpb) * s2;
          ((bf16*)outp)[((size_t)(bi * H_ + h) * seqN + pos) * 64 + d] = (bf16)yv;
        } else if (EPI == 2) {
          int bi = n >> 11, kp = n & (NKV_ - 1);
          ((bf16*)outp)[(size_t)bi * (1024 * NKV_) + (size_t)mrow * NKV_ + kp] =
              (bf16)(x + bias[mrow]);
        } else {
          ((float*)outp)[(size_t)mrow * 1024 + n] = x + bias[n];
        }
      }
    }
}

// ---------------- flash attention (32x32 MFMA, swapped QK^T, in-reg P repack) ----
__device__ __forceinline__ int swz128(int row, int slot) { // 128B rows, 8x16B slots
  return row * 128 + ((slot ^ (row & 7)) << 4);
}

__global__ __launch_bounds__(256)
void attn_kernel(const bf16* __restrict__ Qh, const bf16* __restrict__ Kh,
                 const bf16* __restrict__ Vt, bf16* __restrict__ Ao) {
  __shared__ bf16 Ks[2][64 * 64];
  __shared__ bf16 Vs[2][64 * 64];
  const int tid = threadIdx.x, wq = tid >> 6, l = tid & 63;
  const int q31 = l & 31, h = l >> 5;

  // XCD swizzle: each XCD owns 16 contiguous bh (K/V L2-resident per XCD)
  int bid = blockIdx.x;
  int vid = (bid & 7) * 128 + (bid >> 3);
  const int bh = vid >> 3;
  const int q0 = (vid & 7) * 128;

  // Q fragments (B-operand: lane col = q31, k-octet over d = kt*16 + h*8)
  bf16x8 aq[4];
  {
    const bf16* qrow = Qh + ((size_t)bh * NQ_ + q0 + wq * 32 + q31) * 64;
#pragma unroll
    for (int kt = 0; kt < 4; ++kt) aq[kt] = *(const bf16x8*)(qrow + kt * 16 + h * 8);
  }

  const char* Kbase = (const char*)(Kh + (size_t)bh * NKV_ * 64);
  const char* Vbase = (const char*)(Vt + (size_t)bh * 64 * NKV_);

  auto stageKV = [&](int t, int buf) {
#pragma unroll
    for (int i = 0; i < 2; ++i) {
      int S = i * 256 + tid;
      int row = S >> 3, st = S & 7;
      int gs = st ^ (row & 7);
      gload_lds16(Kbase + (size_t)(t * 64 + row) * 128 + gs * 16,
                  (char*)&Ks[buf][0] + (i * 256 + wq * 64) * 16);
    }
#pragma unroll
    for (int i = 0; i < 2; ++i) {
      int S = i * 256 + tid;
      int row = S >> 3, st = S & 7;
      int gs = st ^ (row & 7);
      gload_lds16(Vbase + (size_t)row * (NKV_ * 2) + (size_t)t * 128 + gs * 16,
                  (char*)&Vs[buf][0] + (i * 256 + wq * 64) * 16);
    }
  };

  float mrun = -3.0e38f, lrun = 0.f;
  f32x16 oaccT[2] = {};

  stageKV(0, 0);
  __syncthreads();

  const float SC = 0.125f * 1.44269504f;  // scale * log2(e)

  for (int t = 0; t < NKV_ / 64; ++t) {
    int buf = t & 1;
    if (t + 1 < NKV_ / 64) stageKV(t + 1, buf ^ 1);

    // S^T[kv, q] = mfma(A=K, B=Q): lane holds col q=q31; rows kv per C/D layout:
    // st[kvt][r] = P[q][kv = kvt*32 + (r&3) + 8*(r>>2) + 4*h]
    f32x16 st[2] = {};
    __builtin_amdgcn_s_setprio(1);
#pragma unroll
    for (int kvt = 0; kvt < 2; ++kvt)
#pragma unroll
      for (int kt = 0; kt < 4; ++kt) {
        bf16x8 kf = *(const bf16x8*)((const char*)&Ks[buf][0] +
                                     swz128(kvt * 32 + q31, kt * 2 + h));
        st[kvt] = __builtin_amdgcn_mfma_f32_32x32x16_bf16(kf, aq[kt], st[kvt], 0, 0, 0);
      }
    __builtin_amdgcn_s_setprio(0);

    // tile max via packed f32 max, then partner half via shfl
    f32x2 m2 = { -3.0e38f, -3.0e38f };
#pragma unroll
    for (int kvt = 0; kvt < 2; ++kvt)
#pragma unroll
      for (int i = 0; i < 8; ++i) {
        f32x2 v = { st[kvt][2 * i], st[kvt][2 * i + 1] };
        m2 = __builtin_elementwise_max(m2, v);
      }
    float ms = fmaxf(m2.x, m2.y);
    ms = fmaxf(ms, __shfl_xor(ms, 32));

    // defer-max (T13): only rescale when tile max outgrows running max by >8 log2
    if (!__all((ms - mrun) * SC <= 8.0f)) {
      float mn = fmaxf(mrun, ms);
      float alpha = exp2f((mrun - mn) * SC);
      mrun = mn;
      lrun *= alpha;
#pragma unroll
      for (int dt = 0; dt < 2; ++dt) oaccT[dt] *= alpha;
    }
    float bterm = mrun * SC;

    // P = exp2(st*SC - bterm)
    f32x2 rs2 = { 0.f, 0.f };
    const f32x2 sc2 = { SC, SC };
    const f32x2 nb2 = { -bterm, -bterm };
#pragma unroll
    for (int kvt = 0; kvt < 2; ++kvt)
#pragma unroll
      for (int i = 0; i < 8; ++i) {
        f32x2 v = { st[kvt][2 * i], st[kvt][2 * i + 1] };
        v = v * sc2 + nb2;
        f32x2 p = { exp2f(v.x), exp2f(v.y) };
        st[kvt][2 * i] = p.x;
        st[kvt][2 * i + 1] = p.y;
        rs2 = rs2 + p;
      }
    float rs = rs2.x + rs2.y;
    rs += __shfl_xor(rs, 32);
    lrun += rs;

    // In-register P^T B-fragment repack (replaces the P LDS round-trip).
    // B-frag for PV, frag index vt = kvt*2+v2: lane (q31,h) needs elem j at
    // kv_local = v2*16 + h*8 + j, i.e. u32 word w = pairs (2w, 2w+1).
    // Own st holds kv_local = (r&3) + 8*(r>>2) + 4*h. Define per kvt:
    //   E0=pk(st0,st1)   E1=pk(st2,st3)    (r0-3:  kv  0-3  +4h)
    //   O0=pk(st4,st5)   O1=pk(st6,st7)    (r4-7:  kv  8-11 +4h)
    //   E2=pk(st8,st9)   E3=pk(st10,st11)  (r8-11: kv 16-19 +4h)
    //   O2=pk(st12,st13) O3=pk(st14,st15)  (r12-15:kv 24-27 +4h)
    // v2=0 frag: h=0 -> [E0,E1, partner.E0, partner.E1]
    //            h=1 -> [partner.O0, partner.O1, O0, O1]
    // v2=1 frag: same with E2,E3 / O2,O3.
    // Partner exchange: give g = h ? E : O, recv r = shfl_xor(g, 32).
    bf16x8 pf[4];
#pragma unroll
    for (int kvt = 0; kvt < 2; ++kvt) {
      u32 E0 = pack2(st[kvt][0],  st[kvt][1]);
      u32 E1 = pack2(st[kvt][2],  st[kvt][3]);
      u32 O0 = pack2(st[kvt][4],  st[kvt][5]);
      u32 O1 = pack2(st[kvt][6],  st[kvt][7]);
      u32 E2 = pack2(st[kvt][8],  st[kvt][9]);
      u32 E3 = pack2(st[kvt][10], st[kvt][11]);
      u32 O2 = pack2(st[kvt][12], st[kvt][13]);
      u32 O3 = pack2(st[kvt][14], st[kvt][15]);
      u32 r0 = (u32)__shfl_xor((int)(h ? E0 : O0), 32);
      u32 r1 = (u32)__shfl_xor((int)(h ? E1 : O1), 32);
      u32 r2 = (u32)__shfl_xor((int)(h ? E2 : O2), 32);
      u32 r3 = (u32)__shfl_xor((int)(h ? E3 : O3), 32);
      u32x4 f0 = { h ? r0 : E0, h ? r1 : E1, h ? O0 : r0, h ? O1 : r1 };
      u32x4 f1 = { h ? r2 : E2, h ? r3 : E3, h ? O2 : r2, h ? O3 : r3 };
      pf[kvt * 2 + 0] = __builtin_bit_cast(bf16x8, f0);
      pf[kvt * 2 + 1] = __builtin_bit_cast(bf16x8, f1);
    }

    // O^T[d, q] += V^T * P^T   (A=V-frag rows d, B=P^T-frag cols q)
    __builtin_amdgcn_s_setprio(1);
#pragma unroll
    for (int dt = 0; dt < 2; ++dt)
#pragma unroll
      for (int vt = 0; vt < 4; ++vt) {
        bf16x8 av = *(const bf16x8*)((const char*)&Vs[buf][0] +
                                     swz128(dt * 32 + q31, vt * 2 + h));
        oaccT[dt] = __builtin_amdgcn_mfma_f32_32x32x16_bf16(av, pf[vt], oaccT[dt], 0, 0, 0);
      }
    __builtin_amdgcn_s_setprio(0);
    __syncthreads();
  }

  // epilogue: normalize, pack bf16 pairs, store (lane q col, 32 d values)
  float inv = 1.f / lrun;
  int b = bh >> 4, hh = bh & 15;
  bf16* orow = Ao + ((size_t)b * NQ_ + q0 + wq * 32 + q31) * D_ + hh * 64;
#pragma unroll
  for (int dt = 0; dt < 2; ++dt)
#pragma unroll
    for (int g = 0; g < 4; ++g) {
      int d = dt * 32 + 8 * g + 4 * h;   // oaccT[dt][4g+m] is at d+m
      u32 p0 = pack2(oaccT[dt][g * 4 + 0] * inv, oaccT[dt][g * 4 + 1] * inv);
      u32 p1 = pack2(oaccT[dt][g * 4 + 2] * inv, oaccT[dt][g * 4 + 3] * inv);
      *(u32*)(orow + d) = p0;
      *(u32*)(orow + d + 2) = p1;
    }
}

// ---------------- launch ----------------
extern "C" void kernel_launch(void* const* d_in, const int* in_sizes, int n_in,
                              void* d_out, int out_size, void* d_ws, size_t ws_size,
                              hipStream_t stream) {
  (void)in_sizes; (void)n_in; (void)out_size; (void)ws_size;
  const float* q_in   = (const float*)d_in[0];
  const float* kv_in  = (const float*)d_in[1];
  const float* q_cos  = (const float*)d_in[2];
  const float* q_sin  = (const float*)d_in[3];
  const float* kv_cos = (const float*)d_in[4];
  const float* kv_sin = (const float*)d_in[5];
  const float* Wq = (const float*)d_in[6];
  const float* bq = (const float*)d_in[7];
  const float* Wk = (const float*)d_in[8];
  const float* bk = (const float*)d_in[9];
  const float* Wv = (const float*)d_in[10];
  const float* bv = (const float*)d_in[11];
  const float* Wo = (const float*)d_in[12];
  const float* bo = (const float*)d_in[13];

  char* ws = (char*)d_ws;
  bf16* qn  = (bf16*)ws;              ws += (size_t)B_ * NQ_ * D_ * 2;    // 16MB (reused for Ao)
  bf16* kvn = (bf16*)ws;              ws += (size_t)B_ * NKV_ * D_ * 2;   // 32MB
  bf16* wqb = (bf16*)ws;              ws += (size_t)D_ * D_ * 2;          // 2MB
  bf16* wkb = (bf16*)ws;              ws += (size_t)D_ * D_ * 2;
  bf16* wvb = (bf16*)ws;              ws += (size_t)D_ * D_ * 2;
  bf16* wob = (bf16*)ws;              ws += (size_t)D_ * D_ * 2;
  bf16* Qh  = (bf16*)ws;              ws += (size_t)B_ * H_ * NQ_ * 64 * 2;   // 16MB
  bf16* Kh  = (bf16*)ws;              ws += (size_t)B_ * H_ * NKV_ * 64 * 2;  // 32MB
  bf16* Vt  = (bf16*)ws;              ws += (size_t)B_ * H_ * 64 * NKV_ * 2;  // 32MB
  bf16* Ao  = qn;  // qn dead after Q projection; reuse

  cvt_w_kernel<<<dim3(1024, 4), 256, 0, stream>>>(Wq, Wk, Wv, Wo, wqb, wkb, wvb, wob);
  ln_bf16_kernel<<<(B_ * NQ_) / 4, 256, 0, stream>>>(q_in, qn);
  ln_bf16_kernel<<<(B_ * NKV_) / 4, 256, 0, stream>>>(kv_in, kvn);

  gemm_bt<0><<<dim3(D_ / 128, (B_ * NQ_) / 128), 256, 0, stream>>>(
      qn, wqb, bq, q_cos, q_sin, (void*)Qh, 10);
  gemm_bt<0><<<dim3(D_ / 128, (B_ * NKV_) / 128), 256, 0, stream>>>(
      kvn, wkb, bk, kv_cos, kv_sin, (void*)Kh, 11);
  gemm_bt<2><<<dim3((B_ * NKV_) / 128, D_ / 128), 256, 0, stream>>>(
      wvb, kvn, bv, nullptr, nullptr, (void*)Vt, 0);

  attn_kernel<<<dim3((B_ * H_ * NQ_) / 128), 256, 0, stream>>>(Qh, Kh, Vt, Ao);

  gemm_bt<3><<<dim3(D_ / 128, (B_ * NQ_) / 128), 256, 0, stream>>>(
      Ao, wob, bo, nullptr, nullptr, d_out, 0);
}

// Round 7
// 524.155 us; speedup vs baseline: 1.0991x; 1.0991x over previous
//
#include <hip/hip_runtime.h>
#include <stdint.h>
#include <stddef.h>

#define B_   8
#define NQ_  1024
#define NKV_ 2048
#define D_   1024
#define H_   16
#define HD_  64

typedef __bf16 bf16;
typedef __bf16 bf16x2 __attribute__((ext_vector_type(2)));
typedef __bf16 bf16x4 __attribute__((ext_vector_type(4)));
typedef __bf16 bf16x8 __attribute__((ext_vector_type(8)));
typedef float  f32x2  __attribute__((ext_vector_type(2)));
typedef float  f32x4  __attribute__((ext_vector_type(4)));
typedef float  f32x16 __attribute__((ext_vector_type(16)));
typedef unsigned int u32;
typedef u32 u32x2 __attribute__((ext_vector_type(2)));
typedef u32 u32x4 __attribute__((ext_vector_type(4)));
typedef unsigned short u16;

__device__ __forceinline__ void gload_lds16(const void* g, void* l) {
  __builtin_amdgcn_global_load_lds((const __attribute__((address_space(1))) void*)g,
                                   (__attribute__((address_space(3))) void*)l, 16, 0, 0);
}

// packed bf16 pair via vector convert -> single v_cvt_pk_bf16_f32
__device__ __forceinline__ u32 pack2(float a, float b) {
  f32x2 v = { a, b };
  return __builtin_bit_cast(u32, __builtin_convertvector(v, bf16x2));
}

// ---------------- weight fp32 -> bf16 ----------------
__global__ void cvt_w_kernel(const float* __restrict__ w0, const float* __restrict__ w1,
                             const float* __restrict__ w2, const float* __restrict__ w3,
                             bf16* __restrict__ o0, bf16* __restrict__ o1,
                             bf16* __restrict__ o2, bf16* __restrict__ o3) {
  const float* s; bf16* d;
  switch (blockIdx.y) {
    case 0: s = w0; d = o0; break;
    case 1: s = w1; d = o1; break;
    case 2: s = w2; d = o2; break;
    default: s = w3; d = o3; break;
  }
  int i = (blockIdx.x * 256 + threadIdx.x) * 4;
  float4 v = *(const float4*)(s + i);
  bf16x4 t = { (bf16)v.x, (bf16)v.y, (bf16)v.z, (bf16)v.w };
  *(bf16x4*)(d + i) = t;
}

// ---------------- packed cos/sin tables (f32 precision) ----------------
__global__ void build_cs_kernel(const float* __restrict__ qc, const float* __restrict__ qs,
                                const float* __restrict__ kc, const float* __restrict__ ks,
                                float2* __restrict__ qcs, float2* __restrict__ kcs) {
  int i = blockIdx.x * 256 + threadIdx.x;
  if (i < NQ_ * 64) {
    qcs[i] = make_float2(qc[i], qs[i]);
  } else {
    int j = i - NQ_ * 64;
    kcs[j] = make_float2(kc[j], ks[j]);
  }
}

// ---------------- LayerNorm rows of 1024, fp32 -> bf16 ----------------
__global__ void ln_bf16_kernel(const float* __restrict__ x, bf16* __restrict__ y) {
  int w = threadIdx.x >> 6, l = threadIdx.x & 63;
  int row = blockIdx.x * 4 + w;
  const float* xr = x + (size_t)row * D_;
  float4 v[4];
#pragma unroll
  for (int k = 0; k < 4; ++k) v[k] = *(const float4*)(xr + k * 256 + l * 4);
  float s = 0.f, ss = 0.f;
#pragma unroll
  for (int k = 0; k < 4; ++k) {
    s  += v[k].x + v[k].y + v[k].z + v[k].w;
    ss += v[k].x * v[k].x + v[k].y * v[k].y + v[k].z * v[k].z + v[k].w * v[k].w;
  }
#pragma unroll
  for (int m = 1; m < 64; m <<= 1) { s += __shfl_xor(s, m); ss += __shfl_xor(ss, m); }
  float mu = s * (1.f / D_);
  float var = ss * (1.f / D_) - mu * mu;
  float rs = rsqrtf(var + 1e-5f);
  bf16* yr = y + (size_t)row * D_;
#pragma unroll
  for (int k = 0; k < 4; ++k) {
    bf16x4 t = { (bf16)((v[k].x - mu) * rs), (bf16)((v[k].y - mu) * rs),
                 (bf16)((v[k].z - mu) * rs), (bf16)((v[k].w - mu) * rs) };
    *(bf16x4*)(yr + k * 256 + l * 4) = t;
  }
}

// ---------------- GEMM: C[m,n] = sum_k A[m,k]*Bw[n,k] (+bias, epilogue) ----------
__device__ __forceinline__ int swz64(int row, int slot) {  // 64B rows, 4x16B slots
  return row * 64 + ((slot ^ ((row >> 1) & 3)) << 4);
}

template<int EPI>
__global__ __launch_bounds__(256)
void gemm_bt(const bf16* __restrict__ A, const bf16* __restrict__ Bw,
             const float* __restrict__ bias,
             const float2* __restrict__ csT,
             void* __restrict__ outp, int seq_shift) {
  __shared__ bf16 As[2][128 * 32];
  __shared__ bf16 Bs[2][128 * 32];
  const int tid = threadIdx.x;
  const int w = tid >> 6, l = tid & 63;
  const int wr = w >> 1, wc = w & 1;
  const int lg = l >> 4, lr = l & 15;
  const int mbase = blockIdx.y * 128, nbase = blockIdx.x * 128;

  f32x4 acc[4][4] = {};

  auto stage = [&](int k0, int buf) {
#pragma unroll
    for (int i = 0; i < 2; ++i) {
      int S = i * 256 + tid;
      int row = S >> 2, st = S & 3;
      int gs = st ^ ((row >> 1) & 3);
      gload_lds16((const char*)(A + ((size_t)(mbase + row) * 1024 + k0)) + gs * 16,
                  (char*)&As[buf][0] + (i * 256 + w * 64) * 16);
    }
#pragma unroll
    for (int i = 0; i < 2; ++i) {
      int S = i * 256 + tid;
      int row = S >> 2, st = S & 3;
      int gs = st ^ ((row >> 1) & 3);
      gload_lds16((const char*)(Bw + ((size_t)(nbase + row) * 1024 + k0)) + gs * 16,
                  (char*)&Bs[buf][0] + (i * 256 + w * 64) * 16);
    }
  };

  stage(0, 0);
  __syncthreads();
  for (int it = 0; it < 32; ++it) {
    int buf = it & 1;
    if (it + 1 < 32) stage((it + 1) * 32, buf ^ 1);
    bf16x8 af[4], bfr[4];
#pragma unroll
    for (int fr = 0; fr < 4; ++fr)
      af[fr] = *(const bf16x8*)((const char*)&As[buf][0] + swz64(wr * 64 + fr * 16 + lr, lg));
#pragma unroll
    for (int fc = 0; fc < 4; ++fc)
      bfr[fc] = *(const bf16x8*)((const char*)&Bs[buf][0] + swz64(wc * 64 + fc * 16 + lr, lg));
#pragma unroll
    for (int fr = 0; fr < 4; ++fr)
#pragma unroll
      for (int fc = 0; fc < 4; ++fc)
        acc[fr][fc] = __builtin_amdgcn_mfma_f32_16x16x32_bf16(af[fr], bfr[fc], acc[fr][fc], 0, 0, 0);
    __syncthreads();
  }

#pragma unroll
  for (int fr = 0; fr < 4; ++fr)
#pragma unroll
    for (int r = 0; r < 4; ++r) {
      int mrow = mbase + wr * 64 + fr * 16 + lg * 4 + r;
#pragma unroll
      for (int fc = 0; fc < 4; ++fc) {
        int n = nbase + wc * 64 + fc * 16 + lr;
        float x = acc[fr][fc][r];
        if (EPI == 0) {
          float xb  = x + bias[n];
          float xpb = acc[fr][fc ^ 2][r] + bias[n ^ 32];
          int d = n & 63, h = n >> 6;
          int seqN = 1 << seq_shift;
          int pos = mrow & (seqN - 1), bi = mrow >> seq_shift;
          float2 cs = csT[pos * 64 + d];
          float yv = xb * cs.x + ((d < 32) ? -xpb : xpb) * cs.y;
          ((bf16*)outp)[((size_t)(bi * H_ + h) * seqN + pos) * 64 + d] = (bf16)yv;
        } else if (EPI == 2) {
          int bi = n >> 11, kp = n & (NKV_ - 1);
          ((bf16*)outp)[(size_t)bi * (1024 * NKV_) + (size_t)mrow * NKV_ + kp] =
              (bf16)(x + bias[mrow]);
        } else {
          ((float*)outp)[(size_t)mrow * 1024 + n] = x + bias[n];
        }
      }
    }
}

// ---------------- flash attention (32x32 MFMA, swapped QK^T, in-reg P repack) ----
__device__ __forceinline__ int swz128(int row, int slot) { // 128B rows, 8x16B slots
  return row * 128 + ((slot ^ (row & 7)) << 4);
}

__global__ __launch_bounds__(256)
void attn_kernel(const bf16* __restrict__ Qh, const bf16* __restrict__ Kh,
                 const bf16* __restrict__ Vt, bf16* __restrict__ Ao) {
  __shared__ bf16 Ks[2][64 * 64];
  __shared__ bf16 Vs[2][64 * 64];
  const int tid = threadIdx.x, wq = tid >> 6, l = tid & 63;
  const int q31 = l & 31, h = l >> 5;

  // XCD swizzle: each XCD owns 16 contiguous bh (K/V L2-resident per XCD)
  int bid = blockIdx.x;
  int vid = (bid & 7) * 128 + (bid >> 3);
  const int bh = vid >> 3;
  const int q0 = (vid & 7) * 128;

  // Q fragments (B-operand: lane col = q31, k-octet over d = kt*16 + h*8)
  bf16x8 aq[4];
  {
    const bf16* qrow = Qh + ((size_t)bh * NQ_ + q0 + wq * 32 + q31) * 64;
#pragma unroll
    for (int kt = 0; kt < 4; ++kt) aq[kt] = *(const bf16x8*)(qrow + kt * 16 + h * 8);
  }

  const char* Kbase = (const char*)(Kh + (size_t)bh * NKV_ * 64);
  const char* Vbase = (const char*)(Vt + (size_t)bh * 64 * NKV_);

  auto stageKV = [&](int t, int buf) {
#pragma unroll
    for (int i = 0; i < 2; ++i) {
      int S = i * 256 + tid;
      int row = S >> 3, st = S & 7;
      int gs = st ^ (row & 7);
      gload_lds16(Kbase + (size_t)(t * 64 + row) * 128 + gs * 16,
                  (char*)&Ks[buf][0] + (i * 256 + wq * 64) * 16);
    }
#pragma unroll
    for (int i = 0; i < 2; ++i) {
      int S = i * 256 + tid;
      int row = S >> 3, st = S & 7;
      int gs = st ^ (row & 7);
      gload_lds16(Vbase + (size_t)row * (NKV_ * 2) + (size_t)t * 128 + gs * 16,
                  (char*)&Vs[buf][0] + (i * 256 + wq * 64) * 16);
    }
  };

  float mrun = -3.0e38f, lrun = 0.f;
  f32x16 oaccT[2] = {};

  stageKV(0, 0);
  __syncthreads();

  const float SC = 0.125f * 1.44269504f;  // scale * log2(e)

  for (int t = 0; t < NKV_ / 64; ++t) {
    int buf = t & 1;
    if (t + 1 < NKV_ / 64) stageKV(t + 1, buf ^ 1);

    // S^T[kv, q] = mfma(A=K, B=Q): lane holds col q=q31; rows kv per C/D layout:
    // st[kvt][r] = P[q][kv = kvt*32 + (r&3) + 8*(r>>2) + 4*h]
    f32x16 st[2] = {};
    __builtin_amdgcn_s_setprio(1);
#pragma unroll
    for (int kvt = 0; kvt < 2; ++kvt)
#pragma unroll
      for (int kt = 0; kt < 4; ++kt) {
        bf16x8 kf = *(const bf16x8*)((const char*)&Ks[buf][0] +
                                     swz128(kvt * 32 + q31, kt * 2 + h));
        st[kvt] = __builtin_amdgcn_mfma_f32_32x32x16_bf16(kf, aq[kt], st[kvt], 0, 0, 0);
      }
    __builtin_amdgcn_s_setprio(0);

    // tile max via packed f32 max, then partner half via shfl
    f32x2 m2 = { -3.0e38f, -3.0e38f };
#pragma unroll
    for (int kvt = 0; kvt < 2; ++kvt)
#pragma unroll
      for (int i = 0; i < 8; ++i) {
        f32x2 v = { st[kvt][2 * i], st[kvt][2 * i + 1] };
        m2 = __builtin_elementwise_max(m2, v);
      }
    float ms = fmaxf(m2.x, m2.y);
    ms = fmaxf(ms, __shfl_xor(ms, 32));

    // defer-max (T13): only rescale when tile max outgrows running max by >8 log2
    if (!__all((ms - mrun) * SC <= 8.0f)) {
      float mn = fmaxf(mrun, ms);
      float alpha = __builtin_amdgcn_exp2f((mrun - mn) * SC);
      mrun = mn;
      lrun *= alpha;
#pragma unroll
      for (int dt = 0; dt < 2; ++dt) oaccT[dt] *= alpha;
    }
    float bterm = mrun * SC;

    // P = exp2(st*SC - bterm): packed fma for args, raw v_exp_f32, packed sum
    f32x2 rs2 = { 0.f, 0.f };
    const f32x2 sc2 = { SC, SC };
    const f32x2 nb2 = { -bterm, -bterm };
#pragma unroll
    for (int kvt = 0; kvt < 2; ++kvt)
#pragma unroll
      for (int i = 0; i < 8; ++i) {
        f32x2 v = { st[kvt][2 * i], st[kvt][2 * i + 1] };
        v = v * sc2 + nb2;
        f32x2 p = { __builtin_amdgcn_exp2f(v.x), __builtin_amdgcn_exp2f(v.y) };
        st[kvt][2 * i] = p.x;
        st[kvt][2 * i + 1] = p.y;
        rs2 = rs2 + p;
      }
    float rs = rs2.x + rs2.y;
    rs += __shfl_xor(rs, 32);
    lrun += rs;

    // In-register P^T B-fragment repack (replaces the P LDS round-trip).
    // B-frag for PV, frag index vt = kvt*2+v2: lane (q31,h) needs elem j at
    // kv_local = v2*16 + h*8 + j, i.e. u32 word w = pairs (2w, 2w+1).
    // Own st holds kv_local = (r&3) + 8*(r>>2) + 4*h. Define per kvt:
    //   E0=pk(st0,st1)   E1=pk(st2,st3)    (r0-3:  kv  0-3  +4h)
    //   O0=pk(st4,st5)   O1=pk(st6,st7)    (r4-7:  kv  8-11 +4h)
    //   E2=pk(st8,st9)   E3=pk(st10,st11)  (r8-11: kv 16-19 +4h)
    //   O2=pk(st12,st13) O3=pk(st14,st15)  (r12-15:kv 24-27 +4h)
    // v2=0 frag: h=0 -> [E0,E1, partner.E0, partner.E1]
    //            h=1 -> [partner.O0, partner.O1, O0, O1]
    // v2=1 frag: same with E2,E3 / O2,O3.
    // Partner exchange: give g = h ? E : O, recv r = shfl_xor(g, 32).
    bf16x8 pf[4];
#pragma unroll
    for (int kvt = 0; kvt < 2; ++kvt) {
      u32 E0 = pack2(st[kvt][0],  st[kvt][1]);
      u32 E1 = pack2(st[kvt][2],  st[kvt][3]);
      u32 O0 = pack2(st[kvt][4],  st[kvt][5]);
      u32 O1 = pack2(st[kvt][6],  st[kvt][7]);
      u32 E2 = pack2(st[kvt][8],  st[kvt][9]);
      u32 E3 = pack2(st[kvt][10], st[kvt][11]);
      u32 O2 = pack2(st[kvt][12], st[kvt][13]);
      u32 O3 = pack2(st[kvt][14], st[kvt][15]);
      u32 r0 = (u32)__shfl_xor((int)(h ? E0 : O0), 32);
      u32 r1 = (u32)__shfl_xor((int)(h ? E1 : O1), 32);
      u32 r2 = (u32)__shfl_xor((int)(h ? E2 : O2), 32);
      u32 r3 = (u32)__shfl_xor((int)(h ? E3 : O3), 32);
      u32x4 f0 = { h ? r0 : E0, h ? r1 : E1, h ? O0 : r0, h ? O1 : r1 };
      u32x4 f1 = { h ? r2 : E2, h ? r3 : E3, h ? O2 : r2, h ? O3 : r3 };
      pf[kvt * 2 + 0] = __builtin_bit_cast(bf16x8, f0);
      pf[kvt * 2 + 1] = __builtin_bit_cast(bf16x8, f1);
    }

    // O^T[d, q] += V^T * P^T   (A=V-frag rows d, B=P^T-frag cols q)
    __builtin_amdgcn_s_setprio(1);
#pragma unroll
    for (int dt = 0; dt < 2; ++dt)
#pragma unroll
      for (int vt = 0; vt < 4; ++vt) {
        bf16x8 av = *(const bf16x8*)((const char*)&Vs[buf][0] +
                                     swz128(dt * 32 + q31, vt * 2 + h));
        oaccT[dt] = __builtin_amdgcn_mfma_f32_32x32x16_bf16(av, pf[vt], oaccT[dt], 0, 0, 0);
      }
    __builtin_amdgcn_s_setprio(0);
    __syncthreads();
  }

  // epilogue: normalize, pack bf16 pairs, store (lane q col, 32 d values)
  float inv = __builtin_amdgcn_rcpf(lrun);
  int b = bh >> 4, hh = bh & 15;
  bf16* orow = Ao + ((size_t)b * NQ_ + q0 + wq * 32 + q31) * D_ + hh * 64;
#pragma unroll
  for (int dt = 0; dt < 2; ++dt)
#pragma unroll
    for (int g = 0; g < 4; ++g) {
      int d = dt * 32 + 8 * g + 4 * h;   // oaccT[dt][4g+m] is at d+m
      u32 p0 = pack2(oaccT[dt][g * 4 + 0] * inv, oaccT[dt][g * 4 + 1] * inv);
      u32 p1 = pack2(oaccT[dt][g * 4 + 2] * inv, oaccT[dt][g * 4 + 3] * inv);
      *(u32*)(orow + d) = p0;
      *(u32*)(orow + d + 2) = p1;
    }
}

// ---------------- launch ----------------
extern "C" void kernel_launch(void* const* d_in, const int* in_sizes, int n_in,
                              void* d_out, int out_size, void* d_ws, size_t ws_size,
                              hipStream_t stream) {
  (void)in_sizes; (void)n_in; (void)out_size; (void)ws_size;
  const float* q_in   = (const float*)d_in[0];
  const float* kv_in  = (const float*)d_in[1];
  const float* q_cos  = (const float*)d_in[2];
  const float* q_sin  = (const float*)d_in[3];
  const float* kv_cos = (const float*)d_in[4];
  const float* kv_sin = (const float*)d_in[5];
  const float* Wq = (const float*)d_in[6];
  const float* bq = (const float*)d_in[7];
  const float* Wk = (const float*)d_in[8];
  const float* bk = (const float*)d_in[9];
  const float* Wv = (const float*)d_in[10];
  const float* bv = (const float*)d_in[11];
  const float* Wo = (const float*)d_in[12];
  const float* bo = (const float*)d_in[13];

  char* ws = (char*)d_ws;
  bf16* qn  = (bf16*)ws;              ws += (size_t)B_ * NQ_ * D_ * 2;    // 16MB (reused for Ao)
  bf16* kvn = (bf16*)ws;              ws += (size_t)B_ * NKV_ * D_ * 2;   // 32MB
  bf16* wqb = (bf16*)ws;              ws += (size_t)D_ * D_ * 2;          // 2MB
  bf16* wkb = (bf16*)ws;              ws += (size_t)D_ * D_ * 2;
  bf16* wvb = (bf16*)ws;              ws += (size_t)D_ * D_ * 2;
  bf16* wob = (bf16*)ws;              ws += (size_t)D_ * D_ * 2;
  bf16* Qh  = (bf16*)ws;              ws += (size_t)B_ * H_ * NQ_ * 64 * 2;   // 16MB
  bf16* Kh  = (bf16*)ws;              ws += (size_t)B_ * H_ * NKV_ * 64 * 2;  // 32MB
  bf16* Vt  = (bf16*)ws;              ws += (size_t)B_ * H_ * 64 * NKV_ * 2;  // 32MB
  float2* qcs = (float2*)ws;          ws += (size_t)NQ_ * 64 * sizeof(float2);   // 512KB
  float2* kcs = (float2*)ws;          ws += (size_t)NKV_ * 64 * sizeof(float2);  // 1MB
  bf16* Ao  = qn;  // qn dead after Q projection; reuse

  cvt_w_kernel<<<dim3(1024, 4), 256, 0, stream>>>(Wq, Wk, Wv, Wo, wqb, wkb, wvb, wob);
  build_cs_kernel<<<(NQ_ * 64 + NKV_ * 64) / 256, 256, 0, stream>>>(
      q_cos, q_sin, kv_cos, kv_sin, qcs, kcs);
  ln_bf16_kernel<<<(B_ * NQ_) / 4, 256, 0, stream>>>(q_in, qn);
  ln_bf16_kernel<<<(B_ * NKV_) / 4, 256, 0, stream>>>(kv_in, kvn);

  gemm_bt<0><<<dim3(D_ / 128, (B_ * NQ_) / 128), 256, 0, stream>>>(
      qn, wqb, bq, qcs, (void*)Qh, 10);
  gemm_bt<0><<<dim3(D_ / 128, (B_ * NKV_) / 128), 256, 0, stream>>>(
      kvn, wkb, bk, kcs, (void*)Kh, 11);
  gemm_bt<2><<<dim3((B_ * NKV_) / 128, D_ / 128), 256, 0, stream>>>(
      wvb, kvn, bv, nullptr, (void*)Vt, 0);

  attn_kernel<<<dim3((B_ * H_ * NQ_) / 128), 256, 0, stream>>>(Qh, Kh, Vt, Ao);

  gemm_bt<3><<<dim3(D_ / 128, (B_ * NQ_) / 128), 256, 0, stream>>>(
      Ao, wob, bo, nullptr, d_out, 0);
}